// Round 9
// baseline (145.536 us; speedup 1.0000x reference)
//
#include <hip/hip_runtime.h>
#include <stdint.h>

#define BSH (32 * 128 * 128)

typedef __attribute__((ext_vector_type(8))) __bf16 bf16x8;
typedef __attribute__((ext_vector_type(4))) float f32x4;

__device__ __forceinline__ unsigned short f2bf(float f) {
  union { float f; unsigned u; } v; v.f = f;
  return (unsigned short)((v.u + 0x7FFFu + ((v.u >> 16) & 1u)) >> 16);
}

__device__ __forceinline__ float fast_exp2(float x) {
#if __has_builtin(__builtin_amdgcn_exp2f)
  return __builtin_amdgcn_exp2f(x);
#else
  float r; asm("v_exp_f32 %0, %1" : "=v"(r) : "v"(x)); return r;
#endif
}
__device__ __forceinline__ float fast_rcp(float x) {
#if __has_builtin(__builtin_amdgcn_rcpf)
  return __builtin_amdgcn_rcpf(x);
#else
  float r; asm("v_rcp_f32 %0, %1" : "=v"(r) : "v"(x)); return r;
#endif
}

// tanh-form GELU (MLP path; ~3e-3 max err vs exact erf GELU).
__device__ __forceinline__ float gelu_f(float y) {
  float u = y * y;
  float p = __builtin_fmaf(u, 0.044715f, 1.0f) * y;
  float w = fast_exp2(p * 2.30220787f);
  return y - y * fast_rcp(1.0f + w);
}

// ---------------------------------------------------------------------------
// Chunked k-major layout: tensor [row][k] stored as chunk(kq,row) =
// base + (kq*128 + row)*8 bf16 (16 B). MFMA fragment read = one
// global_load_dwordx4 / ds_read_b128, 256 B contiguous per quad.
// ---------------------------------------------------------------------------
// Prepass transpose, bank-conflict-clean both sides:
//   write: [s][t] pitch 136 u16, each thread 4 consecutive t (8 B) -> 2-way.
//   read:  16 consecutive lanes walk consecutive tr (2 B stride) -> free.
__device__ __forceinline__ void transpose_block_c(const float* __restrict__ src,
                                                  unsigned short* __restrict__ dst,
                                                  unsigned short* lds) {
  const int tid = threadIdx.x;
  const float4* s4 = (const float4*)(src);
#pragma unroll
  for (int it = 0; it < 16; ++it) {
    int i4 = tid + it * 256;
    float4 v = s4[i4];
    int s = i4 >> 5;
    int t0 = (i4 * 4) & 127;
    unsigned short* pp = lds + s * 136 + t0;
    pp[0] = f2bf(v.x); pp[1] = f2bf(v.y); pp[2] = f2bf(v.z); pp[3] = f2bf(v.w);
  }
  __syncthreads();
#pragma unroll
  for (int it = 0; it < 8; ++it) {
    int c = tid + it * 256;
    int sc = c >> 7, tr = c & 127;  // lanes walk tr -> conflict-free gather
    unsigned short tmp[8] __attribute__((aligned(16)));
#pragma unroll
    for (int e = 0; e < 8; ++e) tmp[e] = lds[(sc * 8 + e) * 136 + tr];
    *(uint4*)(dst + (sc * 128 + tr) * 8) = *(const uint4*)tmp;
  }
}

// XCD owner of j is (j<64 ? j : 127-j) & 7 -- matches mix_kernel's bid&7.
__global__ __launch_bounds__(256) void prepass_kernel(
    const float* __restrict__ W1, const float* __restrict__ trend2,
    const float* __restrict__ Wm1, const float* __restrict__ Wm2,
    unsigned short* __restrict__ W1Tc, unsigned short* __restrict__ T2c,
    unsigned short* __restrict__ Wm1c, unsigned short* __restrict__ Wm2c,
    float* __restrict__ out2) {
  __shared__ unsigned short lds[128 * 136];
  const int bid = blockIdx.x;
  if (bid < 256) {  // W1[stage][j][s][t] -> chunks (kq_s, t), XCD-pinned j map
    int x = bid & 7, i = bid >> 3;   // i 0..31
    int stage = i >> 4, u = i & 15;  // u 0..15
    int m = u & 7, half = u >> 3;
    int jpp = x + 8 * m;             // pair index owned by XCD x
    int j = half ? 127 - jpp : jpp;
    int blk = stage * 128 + j;
    transpose_block_c(W1 + blk * 16384, W1Tc + blk * 16384, lds);
  } else if (bid < 288) {  // trend2[b][s][h] -> chunks (kq_s, h) + fp32 copy
    const int b = bid - 256;
    transpose_block_c(trend2 + b * 16384, T2c + b * 16384, lds);
    const float4* s4 = (const float4*)(trend2 + b * 16384);
    float4* d4 = (float4*)(out2 + b * 16384);
#pragma unroll
    for (int it = 0; it < 16; ++it)
      d4[threadIdx.x + it * 256] = s4[threadIdx.x + it * 256];
  } else if (bid == 288) {
    transpose_block_c(Wm1, Wm1c, lds);
  } else {
    transpose_block_c(Wm2, Wm2c, lds);
  }
}

// ---------------------------------------------------------------------------
// Mix kernel v6: wave-owned complementary j-pairs + register-hoisted B
// (R8) + NEW: both A footprints staged in LDS once per block (cooperative,
// packed [kq][t] rectangles, <=33 KB), so the mt-loops read A via
// ds_read_b128 (~120 cy, hidden) instead of per-mt global loads (the
// latency term that kept mix at ~26 us). The 2 waves share the staged A
// (halves A traffic). One barrier total.
// ---------------------------------------------------------------------------
__global__ __launch_bounds__(128) void mix_kernel(
    const unsigned short* __restrict__ XTc,   // [32] chunks (kq_s, h)
    const unsigned short* __restrict__ W1Tj,  // [128] chunks (kq_s, t), stage
    const float* __restrict__ b1j,            // [128][128] (j, t)
    const float* __restrict__ W2j,            // [128][128] (j, t)
    const float* __restrict__ b2j,            // [128]
    const float* __restrict__ trendR,         // [32][128][128] fp32 residual
    unsigned short* __restrict__ xoutc) {     // [32] chunks (kq_h, j)
  __shared__ __align__(16) unsigned short Alds[16896];  // 33 KB max footprint
  const int bid = blockIdx.x;
  const int b = bid >> 6;
  const int jp = bid & 63;       // bid&7 = jp&7 -> XCD pin matches prepass
  const int js = jp, jb = 127 - jp;
  const int tid = threadIdx.x;
  const int p = tid >> 6;        // wave = h-half
  const int lane = tid & 63;
  const int lane15 = lane & 15;
  const int quad = lane >> 4;

  const int nt_s = (js >> 4) + 1, ks_s = (js >> 5) + 1;  // ks_s <= 2
  const int nt_b = (jb >> 4) + 1, ks_b = (jb >> 5) + 1;  // ks_b = 3 or 4
  const int m16b = nt_b * 16, m16s = nt_s * 16;
  const int base_s = ks_b * nt_b * 512;  // shorts; jb rect = 4ks_b*16nt_b*8

  const unsigned short* Bp = XTc + b * 16384 + (p * 64 + lane15) * 8;
  const float C = -2.45546937f;  // -1.702 * log2(e)

  // ---- hoist B-fragments (cross-XCD operand) into registers, once ----
  bf16x8 Bv[4][4];
#pragma unroll
  for (int ks = 0; ks < 4; ++ks)
    if (ks < ks_b) {
      const int ko = (ks * 4 + quad) * 1024;
      Bv[ks][0] = *(const bf16x8*)(Bp + ko);
      Bv[ks][1] = *(const bf16x8*)(Bp + ko + 128);
      Bv[ks][2] = *(const bf16x8*)(Bp + ko + 256);
      Bv[ks][3] = *(const bf16x8*)(Bp + ko + 384);
    }

  // ---- cooperative stage of both A footprints into LDS ----
  {
    const unsigned short* Ab = W1Tj + jb * 16384;
    for (int kq = 0; kq < 4 * ks_b; ++kq)
      if (tid < m16b)
        *(uint4*)(Alds + (kq * m16b + tid) * 8) =
            *(const uint4*)(Ab + (kq * 128 + tid) * 8);
    const unsigned short* As = W1Tj + js * 16384;
    for (int kq = 0; kq < 4 * ks_s; ++kq)
      if (tid < m16s)
        *(uint4*)(Alds + base_s + (kq * m16s + tid) * 8) =
            *(const uint4*)(As + (kq * 128 + tid) * 8);
  }
  __syncthreads();

  float psum[2][4];
#pragma unroll
  for (int jj = 0; jj < 2; ++jj)
#pragma unroll
    for (int ni = 0; ni < 4; ++ni) psum[jj][ni] = 0.f;

  // ---- pass 1: big j (jb), A from LDS ----
  for (int mt = 0; mt < nt_b; ++mt) {
    f32x4 acc[4];
#pragma unroll
    for (int ni = 0; ni < 4; ++ni) { f32x4 z = {0.f, 0.f, 0.f, 0.f}; acc[ni] = z; }
    const int mo = mt * 16 + lane15;
#pragma unroll
    for (int ks = 0; ks < 4; ++ks)
      if (ks < ks_b) {
        bf16x8 a = *(const bf16x8*)(Alds + ((ks * 4 + quad) * m16b + mo) * 8);
        acc[0] = __builtin_amdgcn_mfma_f32_16x16x32_bf16(a, Bv[ks][0], acc[0], 0, 0, 0);
        acc[1] = __builtin_amdgcn_mfma_f32_16x16x32_bf16(a, Bv[ks][1], acc[1], 0, 0, 0);
        acc[2] = __builtin_amdgcn_mfma_f32_16x16x32_bf16(a, Bv[ks][2], acc[2], 0, 0, 0);
        acc[3] = __builtin_amdgcn_mfma_f32_16x16x32_bf16(a, Bv[ks][3], acc[3], 0, 0, 0);
      }
    const int tb = mt * 16 + quad * 4;
    float4 b1v = *(const float4*)(b1j + jb * 128 + tb);
    float4 w2v = *(const float4*)(W2j + jb * 128 + tb);
#pragma unroll
    for (int r = 0; r < 4; ++r) {
      float b1r = ((const float*)&b1v)[r];
      float w2r = ((const float*)&w2v)[r];
      float cb = C * b1r;
      float bw = b1r * w2r;
#pragma unroll
      for (int ni = 0; ni < 4; ++ni) {
        float a = acc[ni][r];
        float m = __builtin_fmaf(a, C, cb);
        float e = fast_exp2(m);
        float rr2 = fast_rcp(1.0f + e);
        float yw = __builtin_fmaf(a, w2r, bw);
        psum[1][ni] = __builtin_fmaf(yw, rr2, psum[1][ni]);
      }
    }
  }

  // ---- pass 2: small j (js), A from LDS, B already in registers ----
  for (int mt = 0; mt < nt_s; ++mt) {
    f32x4 acc[4];
#pragma unroll
    for (int ni = 0; ni < 4; ++ni) { f32x4 z = {0.f, 0.f, 0.f, 0.f}; acc[ni] = z; }
    const int mo = mt * 16 + lane15;
#pragma unroll
    for (int ks = 0; ks < 2; ++ks)
      if (ks < ks_s) {
        bf16x8 a = *(const bf16x8*)(Alds + base_s + ((ks * 4 + quad) * m16s + mo) * 8);
        acc[0] = __builtin_amdgcn_mfma_f32_16x16x32_bf16(a, Bv[ks][0], acc[0], 0, 0, 0);
        acc[1] = __builtin_amdgcn_mfma_f32_16x16x32_bf16(a, Bv[ks][1], acc[1], 0, 0, 0);
        acc[2] = __builtin_amdgcn_mfma_f32_16x16x32_bf16(a, Bv[ks][2], acc[2], 0, 0, 0);
        acc[3] = __builtin_amdgcn_mfma_f32_16x16x32_bf16(a, Bv[ks][3], acc[3], 0, 0, 0);
      }
    const int tb = mt * 16 + quad * 4;
    float4 b1v = *(const float4*)(b1j + js * 128 + tb);
    float4 w2v = *(const float4*)(W2j + js * 128 + tb);
#pragma unroll
    for (int r = 0; r < 4; ++r) {
      float b1r = ((const float*)&b1v)[r];
      float w2r = ((const float*)&w2v)[r];
      float cb = C * b1r;
      float bw = b1r * w2r;
#pragma unroll
      for (int ni = 0; ni < 4; ++ni) {
        float a = acc[ni][r];
        float m = __builtin_fmaf(a, C, cb);
        float e = fast_exp2(m);
        float rr2 = fast_rcp(1.0f + e);
        float yw = __builtin_fmaf(a, w2r, bw);
        psum[0][ni] = __builtin_fmaf(yw, rr2, psum[0][ni]);
      }
    }
  }

  // quad reduction (sum over the 4 t-rows held across quads)
#pragma unroll
  for (int jj = 0; jj < 2; ++jj)
#pragma unroll
    for (int ni = 0; ni < 4; ++ni) {
      float v = psum[jj][ni];
      v += __shfl_xor(v, 16, 64);
      v += __shfl_xor(v, 32, 64);
      psum[jj][ni] = v;
    }

  if (quad == 0) {  // 16 lanes write 2 j x 4 ni results for this h-half
#pragma unroll
    for (int jj = 0; jj < 2; ++jj) {
      const int j = jj ? jb : js;
      const float bias = b2j[j];
#pragma unroll
      for (int ni = 0; ni < 4; ++ni) {
        const int h = p * 64 + ni * 16 + lane15;
        float v = psum[jj][ni] + bias + trendR[(b * 128 + j) * 128 + h];
        xoutc[b * 16384 + ((h >> 3) * 128 + j) * 8 + (h & 7)] = f2bf(v);
      }
    }
  }
}

// ---------------------------------------------------------------------------
// MLP kernel (known-good from R3): grid 256 = 32 b x 8 tiles of 16 rows.
// ---------------------------------------------------------------------------
__global__ __launch_bounds__(256) void mlp_kernel(
    const unsigned short* __restrict__ Xc,    // [32] chunks (kq_h, j)
    const unsigned short* __restrict__ Wm1c,  // chunks (kq_in, out)
    const unsigned short* __restrict__ Wm2c,
    const float* __restrict__ bm1,
    const float* __restrict__ bm2,
    float* __restrict__ outf,                 // [32][128][128] fp32
    unsigned short* __restrict__ outTc,       // [32] chunks (kq_s, h), optional
    const int write_t) {
  __shared__ __align__(16) unsigned short U[16 * 128];  // chunks (kq_h, row16)
  __shared__ unsigned short ldsT[16 * 136];
  const int bid = blockIdx.x;
  const int b = bid >> 3;
  const int mb = bid & 7;
  const int tid = threadIdx.x;
  const int wave = tid >> 6;
  const int lane = tid & 63;
  const int lane15 = lane & 15;
  const int quad = lane >> 4;

  const unsigned short* Xb = Xc + b * 16384;

  f32x4 acc[2];
  { f32x4 z = {0.f, 0.f, 0.f, 0.f}; acc[0] = z; acc[1] = z; }
#pragma unroll
  for (int ks = 0; ks < 4; ++ks) {  // GEMM1: x @ Wm1
    int kq = ks * 4 + quad;
    bf16x8 a  = *(const bf16x8*)(Xb + (kq * 128 + mb * 16 + lane15) * 8);
    bf16x8 w0 = *(const bf16x8*)(Wm1c + (kq * 128 + wave * 32 + lane15) * 8);
    bf16x8 w1 = *(const bf16x8*)(Wm1c + (kq * 128 + wave * 32 + 16 + lane15) * 8);
    acc[0] = __builtin_amdgcn_mfma_f32_16x16x32_bf16(a, w0, acc[0], 0, 0, 0);
    acc[1] = __builtin_amdgcn_mfma_f32_16x16x32_bf16(a, w1, acc[1], 0, 0, 0);
  }
#pragma unroll
  for (int ni = 0; ni < 2; ++ni) {  // bias+gelu -> U (A-layout for GEMM2)
    int n = wave * 32 + ni * 16 + lane15;
    float bv = bm1[n];
#pragma unroll
    for (int r = 0; r < 4; ++r) {
      int jr = quad * 4 + r;
      U[((n >> 3) * 16 + jr) * 8 + (n & 7)] = f2bf(gelu_f(acc[ni][r] + bv));
    }
  }
  __syncthreads();
  { f32x4 z = {0.f, 0.f, 0.f, 0.f}; acc[0] = z; acc[1] = z; }
#pragma unroll
  for (int ks = 0; ks < 4; ++ks) {  // GEMM2: u @ Wm2
    int kq = ks * 4 + quad;
    bf16x8 a  = *(const bf16x8*)(U + (kq * 16 + lane15) * 8);
    bf16x8 w0 = *(const bf16x8*)(Wm2c + (kq * 128 + wave * 32 + lane15) * 8);
    bf16x8 w1 = *(const bf16x8*)(Wm2c + (kq * 128 + wave * 32 + 16 + lane15) * 8);
    acc[0] = __builtin_amdgcn_mfma_f32_16x16x32_bf16(a, w0, acc[0], 0, 0, 0);
    acc[1] = __builtin_amdgcn_mfma_f32_16x16x32_bf16(a, w1, acc[1], 0, 0, 0);
  }
  {
    float* outb = outf + b * 16384 + mb * 16 * 128;
#pragma unroll
    for (int ni = 0; ni < 2; ++ni) {
      int n = wave * 32 + ni * 16 + lane15;
      float bv = bm2[n];
#pragma unroll
      for (int r = 0; r < 4; ++r) {
        int jr = quad * 4 + r;
        float v = acc[ni][r] + bv;
        outb[jr * 128 + n] = v;
        if (write_t) ldsT[jr * 136 + n] = f2bf(v);
      }
    }
  }
  if (write_t) {  // emit chunks (kq_s, h) for the next mix stage's B-operand
    __syncthreads();
    int h = tid & 127, jr8 = tid >> 7;
    unsigned short tmp[8] __attribute__((aligned(16)));
#pragma unroll
    for (int e = 0; e < 8; ++e) tmp[e] = ldsT[(jr8 * 8 + e) * 136 + h];
    *(uint4*)(outTc + b * 16384 + ((mb * 2 + jr8) * 128 + h) * 8) = *(const uint4*)tmp;
  }
}

// ---------------------------------------------------------------------------
extern "C" void kernel_launch(void* const* d_in, const int* in_sizes, int n_in,
                              void* d_out, int out_size, void* d_ws, size_t ws_size,
                              hipStream_t stream) {
  (void)in_sizes; (void)n_in; (void)out_size; (void)ws_size;
  const float* trend0 = (const float*)d_in[0];
  const float* trend1 = (const float*)d_in[1];
  const float* trend2 = (const float*)d_in[2];
  const float* W1  = (const float*)d_in[3];
  const float* b1  = (const float*)d_in[4];
  const float* W2  = (const float*)d_in[5];
  const float* b2  = (const float*)d_in[6];
  const float* Wm1 = (const float*)d_in[7];
  const float* bm1 = (const float*)d_in[8];
  const float* Wm2 = (const float*)d_in[9];
  const float* bm2 = (const float*)d_in[10];
  float* out = (float*)d_out;
  char* ws = (char*)d_ws;

  unsigned short* W1Tc = (unsigned short*)(ws);             // 8.39 MB (2 stages)
  unsigned short* T2c  = (unsigned short*)(ws + 8388608);   // 1 MB
  unsigned short* x1c  = (unsigned short*)(ws + 9437184);   // 1 MB
  unsigned short* A1Tc = (unsigned short*)(ws + 10485760);  // 1 MB
  unsigned short* x2c  = (unsigned short*)(ws + 11534336);  // 1 MB
  unsigned short* Wm1c = (unsigned short*)(ws + 12582912);  // 32 KB
  unsigned short* Wm2c = (unsigned short*)(ws + 12615680);  // 32 KB

  // outputs: [A2 | A1 | trend2]
  prepass_kernel<<<290, 256, 0, stream>>>(W1, trend2, Wm1, Wm2,
                                          W1Tc, T2c, Wm1c, Wm2c, out + 2 * BSH);
  // stage 0: X = trend2, residual = trend1 -> x1 (bf16 chunks)
  mix_kernel<<<2048, 128, 0, stream>>>(T2c, W1Tc, b1, W2, b2, trend1, x1c);
  // A1 = mlp(x1) -> d_out[1] + A1Tc chunks (next stage's B operand)
  mlp_kernel<<<256, 256, 0, stream>>>(x1c, Wm1c, Wm2c, bm1, bm2,
                                      out + BSH, A1Tc, 1);
  // stage 1: X = A1, residual = trend0 -> x2
  mix_kernel<<<2048, 128, 0, stream>>>(A1Tc, W1Tc + 128 * 16384, b1 + 16384,
                                       W2 + 16384, b2 + 128, trend0, x2c);
  // A2 = mlp(x2) -> d_out[0]
  mlp_kernel<<<256, 256, 0, stream>>>(x2c, Wm1c, Wm2c, bm1, bm2,
                                      out, (unsigned short*)nullptr, 0);
}

// Round 10
// 137.380 us; speedup vs baseline: 1.0594x; 1.0594x over previous
//
#include <hip/hip_runtime.h>
#include <stdint.h>

#define BSH (32 * 128 * 128)

typedef __attribute__((ext_vector_type(8))) __bf16 bf16x8;
typedef __attribute__((ext_vector_type(4))) float f32x4;

__device__ __forceinline__ unsigned short f2bf(float f) {
  union { float f; unsigned u; } v; v.f = f;
  return (unsigned short)((v.u + 0x7FFFu + ((v.u >> 16) & 1u)) >> 16);
}

__device__ __forceinline__ float fast_exp2(float x) {
#if __has_builtin(__builtin_amdgcn_exp2f)
  return __builtin_amdgcn_exp2f(x);
#else
  float r; asm("v_exp_f32 %0, %1" : "=v"(r) : "v"(x)); return r;
#endif
}
__device__ __forceinline__ float fast_rcp(float x) {
#if __has_builtin(__builtin_amdgcn_rcpf)
  return __builtin_amdgcn_rcpf(x);
#else
  float r; asm("v_rcp_f32 %0, %1" : "=v"(r) : "v"(x)); return r;
#endif
}

// tanh-form GELU (MLP path; ~3e-3 max err vs exact erf GELU).
__device__ __forceinline__ float gelu_f(float y) {
  float u = y * y;
  float p = __builtin_fmaf(u, 0.044715f, 1.0f) * y;
  float w = fast_exp2(p * 2.30220787f);
  return y - y * fast_rcp(1.0f + w);
}

// ---------------------------------------------------------------------------
// Chunked k-major layout: tensor [row][k] stored as chunk(kq,row) =
// base + (kq*128 + row)*8 bf16 (16 B). MFMA fragment read = one
// global_load_dwordx4, 256 B contiguous per quad.
// ---------------------------------------------------------------------------
// Prepass transpose, bank-conflict-clean both sides (R9 fix, kept):
//   write: [s][t] pitch 136 u16, each thread 4 consecutive t (8 B) -> 2-way.
//   read:  16 consecutive lanes walk consecutive tr (2 B stride) -> free.
__device__ __forceinline__ void transpose_block_c(const float* __restrict__ src,
                                                  unsigned short* __restrict__ dst,
                                                  unsigned short* lds) {
  const int tid = threadIdx.x;
  const float4* s4 = (const float4*)(src);
#pragma unroll
  for (int it = 0; it < 16; ++it) {
    int i4 = tid + it * 256;
    float4 v = s4[i4];
    int s = i4 >> 5;
    int t0 = (i4 * 4) & 127;
    unsigned short* pp = lds + s * 136 + t0;
    pp[0] = f2bf(v.x); pp[1] = f2bf(v.y); pp[2] = f2bf(v.z); pp[3] = f2bf(v.w);
  }
  __syncthreads();
#pragma unroll
  for (int it = 0; it < 8; ++it) {
    int c = tid + it * 256;
    int sc = c >> 7, tr = c & 127;  // lanes walk tr -> conflict-free gather
    unsigned short tmp[8] __attribute__((aligned(16)));
#pragma unroll
    for (int e = 0; e < 8; ++e) tmp[e] = lds[(sc * 8 + e) * 136 + tr];
    *(uint4*)(dst + (sc * 128 + tr) * 8) = *(const uint4*)tmp;
  }
}

// XCD owner of j is (j<64 ? j : 127-j) & 7 -- matches mix_kernel's bid&7.
__global__ __launch_bounds__(256) void prepass_kernel(
    const float* __restrict__ W1, const float* __restrict__ trend2,
    const float* __restrict__ Wm1, const float* __restrict__ Wm2,
    unsigned short* __restrict__ W1Tc, unsigned short* __restrict__ T2c,
    unsigned short* __restrict__ Wm1c, unsigned short* __restrict__ Wm2c,
    float* __restrict__ out2) {
  __shared__ unsigned short lds[128 * 136];
  const int bid = blockIdx.x;
  if (bid < 256) {  // W1[stage][j][s][t] -> chunks (kq_s, t), XCD-pinned j map
    int x = bid & 7, i = bid >> 3;   // i 0..31
    int stage = i >> 4, u = i & 15;  // u 0..15
    int m = u & 7, half = u >> 3;
    int jpp = x + 8 * m;             // pair index owned by XCD x
    int j = half ? 127 - jpp : jpp;
    int blk = stage * 128 + j;
    transpose_block_c(W1 + blk * 16384, W1Tc + blk * 16384, lds);
  } else if (bid < 288) {  // trend2[b][s][h] -> chunks (kq_s, h) + fp32 copy
    const int b = bid - 256;
    transpose_block_c(trend2 + b * 16384, T2c + b * 16384, lds);
    const float4* s4 = (const float4*)(trend2 + b * 16384);
    float4* d4 = (float4*)(out2 + b * 16384);
#pragma unroll
    for (int it = 0; it < 16; ++it)
      d4[threadIdx.x + it * 256] = s4[threadIdx.x + it * 256];
  } else if (bid == 288) {
    transpose_block_c(Wm1, Wm1c, lds);
  } else {
    transpose_block_c(Wm2, Wm2c, lds);
  }
}

// ---------------------------------------------------------------------------
// Mix kernel v7 = R8's proven structure + mt-split across waves.
// Block = 256 threads / 4 waves: wave = (mh, p); p = h-half (B operand),
// mh = mt-parity. Each wave register-hoists B once (R8 win, 64 VGPR) and
// runs only every other m-tile -> per-wave A-loads, MFMAs, and the gelu
// epilogue all HALVE vs R8 (which duplicated the mt-loop in both waves).
// Cross-wave combine: 512-float LDS bounce + 1 barrier; writer is a
// perfect 256-thread map (v = res[tid] + res[tid+256]).
// No LDS A-staging (R9 lesson: don't trade occupancy for staging).
// ---------------------------------------------------------------------------
__global__ __launch_bounds__(256, 3) void mix_kernel(
    const unsigned short* __restrict__ XTc,   // [32] chunks (kq_s, h)
    const unsigned short* __restrict__ W1Tj,  // [128] chunks (kq_s, t), stage
    const float* __restrict__ b1j,            // [128][128] (j, t)
    const float* __restrict__ W2j,            // [128][128] (j, t)
    const float* __restrict__ b2j,            // [128]
    const float* __restrict__ trendR,         // [32][128][128] fp32 residual
    unsigned short* __restrict__ xoutc) {     // [32] chunks (kq_h, j)
  __shared__ float res[512];
  const int bid = blockIdx.x;
  const int b = bid >> 6;
  const int jp = bid & 63;       // bid&7 = jp&7 -> XCD pin matches prepass
  const int js = jp, jb = 127 - jp;
  const int tid = threadIdx.x;
  const int wave = tid >> 6;     // wave = 2*mh + p
  const int p = wave & 1;        // h-half
  const int mh = wave >> 1;      // mt parity
  const int lane = tid & 63;
  const int lane15 = lane & 15;
  const int quad = lane >> 4;

  const int nt_s = (js >> 4) + 1, ks_s = (js >> 5) + 1;  // ks_s <= 2
  const int nt_b = (jb >> 4) + 1, ks_b = (jb >> 5) + 1;  // ks_b = 3 or 4

  const unsigned short* Bp = XTc + b * 16384 + (p * 64 + lane15) * 8;
  const unsigned short* As = W1Tj + js * 16384 + lane15 * 8;
  const unsigned short* Ab = W1Tj + jb * 16384 + lane15 * 8;
  const float C = -2.45546937f;  // -1.702 * log2(e)

  // ---- hoist B-fragments (cross-XCD operand) into registers, once ----
  bf16x8 Bv[4][4];
#pragma unroll
  for (int ks = 0; ks < 4; ++ks)
    if (ks < ks_b) {
      const int ko = (ks * 4 + quad) * 1024;
      Bv[ks][0] = *(const bf16x8*)(Bp + ko);
      Bv[ks][1] = *(const bf16x8*)(Bp + ko + 128);
      Bv[ks][2] = *(const bf16x8*)(Bp + ko + 256);
      Bv[ks][3] = *(const bf16x8*)(Bp + ko + 384);
    }

  float psum[2][4];
#pragma unroll
  for (int jj = 0; jj < 2; ++jj)
#pragma unroll
    for (int ni = 0; ni < 4; ++ni) psum[jj][ni] = 0.f;

  // ---- pass 1: big j (jb), this wave's mt-parity only ----
  for (int mt = mh; mt < nt_b; mt += 2) {
    f32x4 acc[4];
#pragma unroll
    for (int ni = 0; ni < 4; ++ni) { f32x4 z = {0.f, 0.f, 0.f, 0.f}; acc[ni] = z; }
    const int mo = mt * 128;
#pragma unroll
    for (int ks = 0; ks < 4; ++ks)
      if (ks < ks_b) {
        bf16x8 a = *(const bf16x8*)(Ab + (ks * 4 + quad) * 1024 + mo);
        acc[0] = __builtin_amdgcn_mfma_f32_16x16x32_bf16(a, Bv[ks][0], acc[0], 0, 0, 0);
        acc[1] = __builtin_amdgcn_mfma_f32_16x16x32_bf16(a, Bv[ks][1], acc[1], 0, 0, 0);
        acc[2] = __builtin_amdgcn_mfma_f32_16x16x32_bf16(a, Bv[ks][2], acc[2], 0, 0, 0);
        acc[3] = __builtin_amdgcn_mfma_f32_16x16x32_bf16(a, Bv[ks][3], acc[3], 0, 0, 0);
      }
    const int tb = mt * 16 + quad * 4;
    float4 b1v = *(const float4*)(b1j + jb * 128 + tb);
    float4 w2v = *(const float4*)(W2j + jb * 128 + tb);
#pragma unroll
    for (int r = 0; r < 4; ++r) {
      float b1r = ((const float*)&b1v)[r];
      float w2r = ((const float*)&w2v)[r];
      float cb = C * b1r;
      float bw = b1r * w2r;
#pragma unroll
      for (int ni = 0; ni < 4; ++ni) {
        float a = acc[ni][r];
        float m = __builtin_fmaf(a, C, cb);
        float e = fast_exp2(m);
        float rr2 = fast_rcp(1.0f + e);
        float yw = __builtin_fmaf(a, w2r, bw);
        psum[1][ni] = __builtin_fmaf(yw, rr2, psum[1][ni]);
      }
    }
  }

  // ---- pass 2: small j (js), B already in registers ----
  for (int mt = mh; mt < nt_s; mt += 2) {
    f32x4 acc[4];
#pragma unroll
    for (int ni = 0; ni < 4; ++ni) { f32x4 z = {0.f, 0.f, 0.f, 0.f}; acc[ni] = z; }
    const int mo = mt * 128;
#pragma unroll
    for (int ks = 0; ks < 2; ++ks)  // ks_s <= 2 for js < 64
      if (ks < ks_s) {
        bf16x8 a = *(const bf16x8*)(As + (ks * 4 + quad) * 1024 + mo);
        acc[0] = __builtin_amdgcn_mfma_f32_16x16x32_bf16(a, Bv[ks][0], acc[0], 0, 0, 0);
        acc[1] = __builtin_amdgcn_mfma_f32_16x16x32_bf16(a, Bv[ks][1], acc[1], 0, 0, 0);
        acc[2] = __builtin_amdgcn_mfma_f32_16x16x32_bf16(a, Bv[ks][2], acc[2], 0, 0, 0);
        acc[3] = __builtin_amdgcn_mfma_f32_16x16x32_bf16(a, Bv[ks][3], acc[3], 0, 0, 0);
      }
    const int tb = mt * 16 + quad * 4;
    float4 b1v = *(const float4*)(b1j + js * 128 + tb);
    float4 w2v = *(const float4*)(W2j + js * 128 + tb);
#pragma unroll
    for (int r = 0; r < 4; ++r) {
      float b1r = ((const float*)&b1v)[r];
      float w2r = ((const float*)&w2v)[r];
      float cb = C * b1r;
      float bw = b1r * w2r;
#pragma unroll
      for (int ni = 0; ni < 4; ++ni) {
        float a = acc[ni][r];
        float m = __builtin_fmaf(a, C, cb);
        float e = fast_exp2(m);
        float rr2 = fast_rcp(1.0f + e);
        float yw = __builtin_fmaf(a, w2r, bw);
        psum[0][ni] = __builtin_fmaf(yw, rr2, psum[0][ni]);
      }
    }
  }

  // quad reduction (sum over the 4 t-rows held across quads)
#pragma unroll
  for (int jj = 0; jj < 2; ++jj)
#pragma unroll
    for (int ni = 0; ni < 4; ++ni) {
      float v = psum[jj][ni];
      v += __shfl_xor(v, 16, 64);
      v += __shfl_xor(v, 32, 64);
      psum[jj][ni] = v;
    }

  // cross-wave (mt-parity) combine via LDS: idx = wave*128 + jj*64 + ni*16 + l
  if (quad == 0) {
#pragma unroll
    for (int jj = 0; jj < 2; ++jj)
#pragma unroll
      for (int ni = 0; ni < 4; ++ni)
        res[wave * 128 + jj * 64 + ni * 16 + lane15] = psum[jj][ni];
  }
  __syncthreads();
  {
    // tid = p*128 + jj*64 + ni*16 + l  ->  partner at tid + 256 (mh=1)
    const int l = tid & 15;
    const int ni = (tid >> 4) & 3;
    const int jj = (tid >> 6) & 1;
    const int pp = tid >> 7;
    const int j = jj ? jb : js;
    const int h = pp * 64 + ni * 16 + l;
    float v = res[tid] + res[tid + 256] + b2j[j] +
              trendR[(b * 128 + j) * 128 + h];
    xoutc[b * 16384 + ((h >> 3) * 128 + j) * 8 + (h & 7)] = f2bf(v);
  }
}

// ---------------------------------------------------------------------------
// MLP kernel (known-good from R3): grid 256 = 32 b x 8 tiles of 16 rows.
// ---------------------------------------------------------------------------
__global__ __launch_bounds__(256) void mlp_kernel(
    const unsigned short* __restrict__ Xc,    // [32] chunks (kq_h, j)
    const unsigned short* __restrict__ Wm1c,  // chunks (kq_in, out)
    const unsigned short* __restrict__ Wm2c,
    const float* __restrict__ bm1,
    const float* __restrict__ bm2,
    float* __restrict__ outf,                 // [32][128][128] fp32
    unsigned short* __restrict__ outTc,       // [32] chunks (kq_s, h), optional
    const int write_t) {
  __shared__ __align__(16) unsigned short U[16 * 128];  // chunks (kq_h, row16)
  __shared__ unsigned short ldsT[16 * 136];
  const int bid = blockIdx.x;
  const int b = bid >> 3;
  const int mb = bid & 7;
  const int tid = threadIdx.x;
  const int wave = tid >> 6;
  const int lane = tid & 63;
  const int lane15 = lane & 15;
  const int quad = lane >> 4;

  const unsigned short* Xb = Xc + b * 16384;

  f32x4 acc[2];
  { f32x4 z = {0.f, 0.f, 0.f, 0.f}; acc[0] = z; acc[1] = z; }
#pragma unroll
  for (int ks = 0; ks < 4; ++ks) {  // GEMM1: x @ Wm1
    int kq = ks * 4 + quad;
    bf16x8 a  = *(const bf16x8*)(Xb + (kq * 128 + mb * 16 + lane15) * 8);
    bf16x8 w0 = *(const bf16x8*)(Wm1c + (kq * 128 + wave * 32 + lane15) * 8);
    bf16x8 w1 = *(const bf16x8*)(Wm1c + (kq * 128 + wave * 32 + 16 + lane15) * 8);
    acc[0] = __builtin_amdgcn_mfma_f32_16x16x32_bf16(a, w0, acc[0], 0, 0, 0);
    acc[1] = __builtin_amdgcn_mfma_f32_16x16x32_bf16(a, w1, acc[1], 0, 0, 0);
  }
#pragma unroll
  for (int ni = 0; ni < 2; ++ni) {  // bias+gelu -> U (A-layout for GEMM2)
    int n = wave * 32 + ni * 16 + lane15;
    float bv = bm1[n];
#pragma unroll
    for (int r = 0; r < 4; ++r) {
      int jr = quad * 4 + r;
      U[((n >> 3) * 16 + jr) * 8 + (n & 7)] = f2bf(gelu_f(acc[ni][r] + bv));
    }
  }
  __syncthreads();
  { f32x4 z = {0.f, 0.f, 0.f, 0.f}; acc[0] = z; acc[1] = z; }
#pragma unroll
  for (int ks = 0; ks < 4; ++ks) {  // GEMM2: u @ Wm2
    int kq = ks * 4 + quad;
    bf16x8 a  = *(const bf16x8*)(U + (kq * 16 + lane15) * 8);
    bf16x8 w0 = *(const bf16x8*)(Wm2c + (kq * 128 + wave * 32 + lane15) * 8);
    bf16x8 w1 = *(const bf16x8*)(Wm2c + (kq * 128 + wave * 32 + 16 + lane15) * 8);
    acc[0] = __builtin_amdgcn_mfma_f32_16x16x32_bf16(a, w0, acc[0], 0, 0, 0);
    acc[1] = __builtin_amdgcn_mfma_f32_16x16x32_bf16(a, w1, acc[1], 0, 0, 0);
  }
  {
    float* outb = outf + b * 16384 + mb * 16 * 128;
#pragma unroll
    for (int ni = 0; ni < 2; ++ni) {
      int n = wave * 32 + ni * 16 + lane15;
      float bv = bm2[n];
#pragma unroll
      for (int r = 0; r < 4; ++r) {
        int jr = quad * 4 + r;
        float v = acc[ni][r] + bv;
        outb[jr * 128 + n] = v;
        if (write_t) ldsT[jr * 136 + n] = f2bf(v);
      }
    }
  }
  if (write_t) {  // emit chunks (kq_s, h) for the next mix stage's B-operand
    __syncthreads();
    int h = tid & 127, jr8 = tid >> 7;
    unsigned short tmp[8] __attribute__((aligned(16)));
#pragma unroll
    for (int e = 0; e < 8; ++e) tmp[e] = ldsT[(jr8 * 8 + e) * 136 + h];
    *(uint4*)(outTc + b * 16384 + ((mb * 2 + jr8) * 128 + h) * 8) = *(const uint4*)tmp;
  }
}

// ---------------------------------------------------------------------------
extern "C" void kernel_launch(void* const* d_in, const int* in_sizes, int n_in,
                              void* d_out, int out_size, void* d_ws, size_t ws_size,
                              hipStream_t stream) {
  (void)in_sizes; (void)n_in; (void)out_size; (void)ws_size;
  const float* trend0 = (const float*)d_in[0];
  const float* trend1 = (const float*)d_in[1];
  const float* trend2 = (const float*)d_in[2];
  const float* W1  = (const float*)d_in[3];
  const float* b1  = (const float*)d_in[4];
  const float* W2  = (const float*)d_in[5];
  const float* b2  = (const float*)d_in[6];
  const float* Wm1 = (const float*)d_in[7];
  const float* bm1 = (const float*)d_in[8];
  const float* Wm2 = (const float*)d_in[9];
  const float* bm2 = (const float*)d_in[10];
  float* out = (float*)d_out;
  char* ws = (char*)d_ws;

  unsigned short* W1Tc = (unsigned short*)(ws);             // 8.39 MB (2 stages)
  unsigned short* T2c  = (unsigned short*)(ws + 8388608);   // 1 MB
  unsigned short* x1c  = (unsigned short*)(ws + 9437184);   // 1 MB
  unsigned short* A1Tc = (unsigned short*)(ws + 10485760);  // 1 MB
  unsigned short* x2c  = (unsigned short*)(ws + 11534336);  // 1 MB
  unsigned short* Wm1c = (unsigned short*)(ws + 12582912);  // 32 KB
  unsigned short* Wm2c = (unsigned short*)(ws + 12615680);  // 32 KB

  // outputs: [A2 | A1 | trend2]
  prepass_kernel<<<290, 256, 0, stream>>>(W1, trend2, Wm1, Wm2,
                                          W1Tc, T2c, Wm1c, Wm2c, out + 2 * BSH);
  // stage 0: X = trend2, residual = trend1 -> x1 (bf16 chunks)
  mix_kernel<<<2048, 256, 0, stream>>>(T2c, W1Tc, b1, W2, b2, trend1, x1c);
  // A1 = mlp(x1) -> d_out[1] + A1Tc chunks (next stage's B operand)
  mlp_kernel<<<256, 256, 0, stream>>>(x1c, Wm1c, Wm2c, bm1, bm2,
                                      out + BSH, A1Tc, 1);
  // stage 1: X = A1, residual = trend0 -> x2
  mix_kernel<<<2048, 256, 0, stream>>>(A1Tc, W1Tc + 128 * 16384, b1 + 16384,
                                       W2 + 16384, b2 + 128, trend0, x2c);
  // A2 = mlp(x2) -> d_out[0]
  mlp_kernel<<<256, 256, 0, stream>>>(x2c, Wm1c, Wm2c, bm1, bm2,
                                      out, (unsigned short*)nullptr, 0);
}